// Round 7
// baseline (139.607 us; speedup 1.0000x reference)
//
#include <hip/hip_runtime.h>

typedef __attribute__((ext_vector_type(8))) short short8;
typedef __attribute__((ext_vector_type(4))) short short4_t;
typedef __attribute__((ext_vector_type(4))) float f32x4;

#define NEGBIG -1e10f

__device__ __forceinline__ unsigned short f2bf(float x) {
  unsigned int u = __float_as_uint(x);
  u += 0x7FFFu + ((u >> 16) & 1u);          // round-to-nearest-even
  return (unsigned short)(u >> 16);
}
// pack two f32 -> bf16x2 (a in low16, b in high16), RNE
__device__ __forceinline__ unsigned pack2(float a, float b) {
  unsigned ua = __float_as_uint(a), ub = __float_as_uint(b);
  ua += 0x7FFFu + ((ua >> 16) & 1u);
  ub += 0x7FFFu + ((ub >> 16) & 1u);
  return (ua >> 16) | (ub & 0xFFFF0000u);
}
__device__ __forceinline__ float lo_bf(unsigned p) { return __uint_as_float(p << 16); }
__device__ __forceinline__ float hi_bf(unsigned p) { return __uint_as_float(p & 0xFFFF0000u); }
__device__ __forceinline__ float bfu(unsigned short h) { return __uint_as_float(((unsigned)h) << 16); }

__device__ __forceinline__ float4 mul4(float4 a, float s) {
  float4 r; r.x = a.x*s; r.y = a.y*s; r.z = a.z*s; r.w = a.w*s; return r;
}
__device__ __forceinline__ float4 add4(float4 a, float4 b) {
  float4 r; r.x = a.x+b.x; r.y = a.y+b.y; r.z = a.z+b.z; r.w = a.w+b.w; return r;
}

// ---------------- pool partial: quarter-panel flash partials ----------------
// Grid 8192 = 2048 panels x 4 quarters. Block = 4 waves; wave owns only 4
// tokens, loaded as 2-token batches of 6 INDEPENDENT float4 loads that are
// consumed immediately (dot + bf16 pack) -> high per-wave MLP, short register
// lifetimes, no state crossing the softmax. (256,4): no cap -> no spill.
__global__ __launch_bounds__(256, 4) void pool_partial(
    const float* __restrict__ left, const float* __restrict__ right,
    const float* __restrict__ femb_l, const float* __restrict__ femb_r,
    unsigned short* __restrict__ partials,   // [8192][768] bf16 (unnormalized)
    float4* __restrict__ meta)               // [8192] (M, S, nz, 0)
{
  int bid     = blockIdx.x;     // 0..8191
  int panel   = bid >> 2;       // 0..2047
  int quarter = bid & 3;
  int side    = panel >> 10;
  int rem     = panel & 1023;   // b*4 + f
  int f       = rem & 3;
  const float* v    = (side ? right : left) + (size_t)rem * 64 * 768 + (size_t)quarter * 16 * 768;
  const float* femb = (side ? femb_r : femb_l) + f * 768;

  int tid = threadIdx.x, wave = tid >> 6, lane = tid & 63;

  const float4* fp = (const float4*)femb;
  float4 f0 = fp[lane], f1 = fp[lane + 64], f2 = fp[lane + 128];

  const float4* vp = (const float4*)(v + (size_t)wave * 4 * 768);

  float d[4];
  unsigned pk[4][6];
  unsigned nzmask = 0;

  // ---- Phase 1: 2 batches x 2 tokens; 6 loads in flight per batch ----
  #pragma unroll
  for (int g = 0; g < 2; ++g) {
    const float4* ta = vp + (g * 2 + 0) * 192 + lane;
    const float4* tb = vp + (g * 2 + 1) * 192 + lane;
    float4 xa0 = ta[0], xa1 = ta[64], xa2 = ta[128];
    float4 xb0 = tb[0], xb1 = tb[64], xb2 = tb[128];

    int t0 = g * 2, t1 = g * 2 + 1;
    d[t0] = xa0.x*f0.x + xa0.y*f0.y + xa0.z*f0.z + xa0.w*f0.w
          + xa1.x*f1.x + xa1.y*f1.y + xa1.z*f1.z + xa1.w*f1.w
          + xa2.x*f2.x + xa2.y*f2.y + xa2.z*f2.z + xa2.w*f2.w;
    unsigned nza = __float_as_uint(xa0.x) | __float_as_uint(xa0.y)
                 | __float_as_uint(xa0.z) | __float_as_uint(xa0.w)
                 | __float_as_uint(xa1.x) | __float_as_uint(xa1.y)
                 | __float_as_uint(xa1.z) | __float_as_uint(xa1.w)
                 | __float_as_uint(xa2.x) | __float_as_uint(xa2.y)
                 | __float_as_uint(xa2.z) | __float_as_uint(xa2.w);
    nzmask |= (nza != 0u) ? (1u << t0) : 0u;
    pk[t0][0] = pack2(xa0.x, xa0.y); pk[t0][1] = pack2(xa0.z, xa0.w);
    pk[t0][2] = pack2(xa1.x, xa1.y); pk[t0][3] = pack2(xa1.z, xa1.w);
    pk[t0][4] = pack2(xa2.x, xa2.y); pk[t0][5] = pack2(xa2.z, xa2.w);

    d[t1] = xb0.x*f0.x + xb0.y*f0.y + xb0.z*f0.z + xb0.w*f0.w
          + xb1.x*f1.x + xb1.y*f1.y + xb1.z*f1.z + xb1.w*f1.w
          + xb2.x*f2.x + xb2.y*f2.y + xb2.z*f2.z + xb2.w*f2.w;
    unsigned nzb = __float_as_uint(xb0.x) | __float_as_uint(xb0.y)
                 | __float_as_uint(xb0.z) | __float_as_uint(xb0.w)
                 | __float_as_uint(xb1.x) | __float_as_uint(xb1.y)
                 | __float_as_uint(xb1.z) | __float_as_uint(xb1.w)
                 | __float_as_uint(xb2.x) | __float_as_uint(xb2.y)
                 | __float_as_uint(xb2.z) | __float_as_uint(xb2.w);
    nzmask |= (nzb != 0u) ? (1u << t1) : 0u;
    pk[t1][0] = pack2(xb0.x, xb0.y); pk[t1][1] = pack2(xb0.z, xb0.w);
    pk[t1][2] = pack2(xb1.x, xb1.y); pk[t1][3] = pack2(xb1.z, xb1.w);
    pk[t1][4] = pack2(xb2.x, xb2.y); pk[t1][5] = pack2(xb2.z, xb2.w);
  }

  // ---- Phase 2: 5 pipelined shuffle-reduce chains ----
  #pragma unroll
  for (int sh = 32; sh > 0; sh >>= 1) {
    d[0] += __shfl_xor(d[0], sh);
    d[1] += __shfl_xor(d[1], sh);
    d[2] += __shfl_xor(d[2], sh);
    d[3] += __shfl_xor(d[3], sh);
    nzmask |= __shfl_xor(nzmask, sh);
  }

  // ---- Phase 3: wave-local softmax pieces over 4 tokens ----
  float l[4], e[4];
  #pragma unroll
  for (int t = 0; t < 4; ++t)
    l[t] = d[t] + (((nzmask >> t) & 1u) ? 0.f : NEGBIG);
  float m_w = fmaxf(fmaxf(l[0], l[1]), fmaxf(l[2], l[3]));
  #pragma unroll
  for (int t = 0; t < 4; ++t) e[t] = __expf(l[t] - m_w);
  float s_w = (e[0] + e[1]) + (e[2] + e[3]);

  __shared__ float m_lds[4], s_lds[4];
  __shared__ int   nz_lds[4];
  __shared__ float acc_lds[4 * 768];   // 12 KB

  if (lane == 0) { m_lds[wave] = m_w; s_lds[wave] = s_w; nz_lds[wave] = (nzmask != 0u); }

  // ---- accumulate from packed registers ----
  float4 A0 = {0,0,0,0}, A1 = {0,0,0,0}, A2 = {0,0,0,0};
  #pragma unroll
  for (int t = 0; t < 4; ++t) {
    float c = e[t];
    A0.x += c * lo_bf(pk[t][0]); A0.y += c * hi_bf(pk[t][0]);
    A0.z += c * lo_bf(pk[t][1]); A0.w += c * hi_bf(pk[t][1]);
    A1.x += c * lo_bf(pk[t][2]); A1.y += c * hi_bf(pk[t][2]);
    A1.z += c * lo_bf(pk[t][3]); A1.w += c * hi_bf(pk[t][3]);
    A2.x += c * lo_bf(pk[t][4]); A2.y += c * hi_bf(pk[t][4]);
    A2.z += c * lo_bf(pk[t][5]); A2.w += c * hi_bf(pk[t][5]);
  }

  __syncthreads();
  float M = fmaxf(fmaxf(m_lds[0], m_lds[1]), fmaxf(m_lds[2], m_lds[3]));
  float S = s_lds[0] * __expf(m_lds[0] - M) + s_lds[1] * __expf(m_lds[1] - M)
          + s_lds[2] * __expf(m_lds[2] - M) + s_lds[3] * __expf(m_lds[3] - M);
  float scale = __expf(m_w - M);   // unnormalized; S goes in meta

  float4* al = (float4*)acc_lds;
  al[wave * 192 +       lane] = mul4(A0, scale);
  al[wave * 192 +  64 + lane] = mul4(A1, scale);
  al[wave * 192 + 128 + lane] = mul4(A2, scale);
  __syncthreads();

  if (tid < 192) {
    float4 A = add4(add4(al[tid], al[192 + tid]),
                    add4(al[384 + tid], al[576 + tid]));
    ushort4 o;
    o.x = f2bf(A.x); o.y = f2bf(A.y); o.z = f2bf(A.z); o.w = f2bf(A.w);
    ((ushort4*)(partials + (size_t)bid * 768))[tid] = o;
  }
  if (tid == 192) {
    int has = nz_lds[0] | nz_lds[1] | nz_lds[2] | nz_lds[3];
    float4 mt; mt.x = M; mt.y = S; mt.z = has ? 1.f : 0.f; mt.w = 0.f;
    meta[bid] = mt;
  }
}

// ---------------- pool merge: combine 4 quarter-panels -> bf16 concat ------
__global__ __launch_bounds__(192) void pool_merge(
    const unsigned short* __restrict__ partials, const float4* __restrict__ meta,
    const float* __restrict__ empty_attr,
    unsigned short* __restrict__ concat)   // [B, 8, 768] bf16
{
  int panel = blockIdx.x;     // 0..2047
  int tid = threadIdx.x;      // 0..191
  int side = panel >> 10;
  int rem  = panel & 1023;
  int f    = rem & 3;
  int b    = rem >> 2;

  int p4 = panel * 4;
  float4 mt0 = meta[p4], mt1 = meta[p4 + 1], mt2 = meta[p4 + 2], mt3 = meta[p4 + 3];
  float M = fmaxf(fmaxf(mt0.x, mt1.x), fmaxf(mt2.x, mt3.x));
  float sc0 = __expf(mt0.x - M), sc1 = __expf(mt1.x - M);
  float sc2 = __expf(mt2.x - M), sc3 = __expf(mt3.x - M);
  float S = mt0.y * sc0 + mt1.y * sc1 + mt2.y * sc2 + mt3.y * sc3;
  int has = (mt0.z + mt1.z + mt2.z + mt3.z) != 0.f;

  ushort4 q0 = ((const ushort4*)(partials + (size_t)(p4 + 0) * 768))[tid];
  ushort4 q1 = ((const ushort4*)(partials + (size_t)(p4 + 1) * 768))[tid];
  ushort4 q2 = ((const ushort4*)(partials + (size_t)(p4 + 2) * 768))[tid];
  ushort4 q3 = ((const ushort4*)(partials + (size_t)(p4 + 3) * 768))[tid];

  float4 r;
  if (has) {
    float i0 = sc0 / S, i1 = sc1 / S, i2 = sc2 / S, i3 = sc3 / S;
    r.x = bfu(q0.x)*i0 + bfu(q1.x)*i1 + bfu(q2.x)*i2 + bfu(q3.x)*i3;
    r.y = bfu(q0.y)*i0 + bfu(q1.y)*i1 + bfu(q2.y)*i2 + bfu(q3.y)*i3;
    r.z = bfu(q0.z)*i0 + bfu(q1.z)*i1 + bfu(q2.z)*i2 + bfu(q3.z)*i3;
    r.w = bfu(q0.w)*i0 + bfu(q1.w)*i1 + bfu(q2.w)*i2 + bfu(q3.w)*i3;
  } else {
    r = ((const float4*)empty_attr)[tid];
  }
  ushort4 o;
  o.x = f2bf(r.x); o.y = f2bf(r.y); o.z = f2bf(r.z); o.w = f2bf(r.w);
  size_t base = ((size_t)b * 8 + side * 4 + f) * 192;
  ((ushort4*)concat)[base + tid] = o;
}

// ---------------- GEMM1 split-K ----------------
// A [256,6144] bf16 (K-contig). W1 [1600,6144] f32 (K-contig).
// Grid (100 col-tiles, 8 K-chunks). Each block stages its EXCLUSIVE
// 16col x 768K W1 tile in LDS (bf16) -> W1 read once total.
__global__ __launch_bounds__(256) void gemm1_kernel(
    const unsigned short* __restrict__ A,
    const float* __restrict__ W1,
    float* __restrict__ Hpart)
{
  const int K = 6144, N = 1600, KC = 768;
  int colb = blockIdx.x;          // 0..99
  int kc   = blockIdx.y;          // 0..7
  int col0 = colb * 16;
  int tid = threadIdx.x, wave = tid >> 6, lane = tid & 63;

  __shared__ short wlds[96 * 16 * 8];

  const float* wsrc = W1 + (size_t)col0 * K + kc * KC;
  #pragma unroll
  for (int i = 0; i < 12; ++i) {
    int flat4 = tid + 256 * i;
    int col = flat4 / 192;
    int k   = (flat4 % 192) * 4;
    float4 w = *(const float4*)(wsrc + (size_t)col * K + k);
    short4_t o;
    o[0] = (short)f2bf(w.x); o[1] = (short)f2bf(w.y);
    o[2] = (short)f2bf(w.z); o[3] = (short)f2bf(w.w);
    *(short4_t*)(wlds + (k >> 3) * 128 + col * 8 + (k & 7)) = o;
  }
  __syncthreads();

  int lr = lane & 15;
  const short* a0 = (const short*)A + (size_t)(wave * 64 + lr) * K + kc * KC + (lane >> 4) * 8;
  const short* bptr = wlds + (lane >> 4) * 128 + lr * 8;

  f32x4 acc0 = {}, acc1 = {}, acc2 = {}, acc3 = {};

  #pragma unroll 4
  for (int ks = 0; ks < 24; ++ks) {
    short8 bf  = *(const short8*)(bptr + ks * 512);
    short8 af0 = *(const short8*)(a0 + ks * 32);
    short8 af1 = *(const short8*)(a0 + ks * 32 + 16 * K);
    short8 af2 = *(const short8*)(a0 + ks * 32 + 32 * K);
    short8 af3 = *(const short8*)(a0 + ks * 32 + 48 * K);
    acc0 = __builtin_amdgcn_mfma_f32_16x16x32_bf16(af0, bf, acc0, 0, 0, 0);
    acc1 = __builtin_amdgcn_mfma_f32_16x16x32_bf16(af1, bf, acc1, 0, 0, 0);
    acc2 = __builtin_amdgcn_mfma_f32_16x16x32_bf16(af2, bf, acc2, 0, 0, 0);
    acc3 = __builtin_amdgcn_mfma_f32_16x16x32_bf16(af3, bf, acc3, 0, 0, 0);
  }

  int ccol = lane & 15;
  int crow = (lane >> 4) * 4;
  float* hp = Hpart + (size_t)kc * 256 * N + (size_t)col0 + ccol;
  f32x4 accs[4] = {acc0, acc1, acc2, acc3};
  #pragma unroll
  for (int i = 0; i < 4; ++i) {
    int r = wave * 64 + i * 16 + crow;
    #pragma unroll
    for (int q = 0; q < 4; ++q)
      hp[(size_t)(r + q) * N] = accs[i][q];
  }
}

// ---------------- epilogue: reduce split-K + bias + relu + head GEMM -------
__global__ __launch_bounds__(256) void epilogue_kernel(
    const float* __restrict__ Hpart, const float* __restrict__ b1,
    const float* __restrict__ W2, const float* __restrict__ b2,
    float* __restrict__ out)
{
  const int N = 1600;
  int b = blockIdx.x, tid = threadIdx.x;
  int wave = tid >> 6, lane = tid & 63;
  float s0 = 0.f, s1 = 0.f;
  for (int c = tid; c < N; c += 256) {
    float acc = 0.f;
    #pragma unroll
    for (int kc = 0; kc < 8; ++kc)
      acc += Hpart[((size_t)kc * 256 + b) * N + c];
    float h = fmaxf(acc + b1[c], 0.f);
    s0 += h * W2[c];
    s1 += h * W2[N + c];
  }
  #pragma unroll
  for (int s = 32; s > 0; s >>= 1) {
    s0 += __shfl_xor(s0, s);
    s1 += __shfl_xor(s1, s);
  }
  __shared__ float r0[4], r1[4];
  if (lane == 0) { r0[wave] = s0; r1[wave] = s1; }
  __syncthreads();
  if (tid == 0) {
    out[b * 2 + 0] = r0[0] + r0[1] + r0[2] + r0[3] + b2[0];
    out[b * 2 + 1] = r1[0] + r1[1] + r1[2] + r1[3] + b2[1];
  }
}

extern "C" void kernel_launch(void* const* d_in, const int* in_sizes, int n_in,
                              void* d_out, int out_size, void* d_ws, size_t ws_size,
                              hipStream_t stream) {
  const float* left       = (const float*)d_in[0];
  const float* right      = (const float*)d_in[1];
  const float* femb_l     = (const float*)d_in[2];
  const float* femb_r     = (const float*)d_in[3];
  const float* empty_attr = (const float*)d_in[4];
  const float* W1         = (const float*)d_in[5];
  const float* b1         = (const float*)d_in[6];
  const float* W2         = (const float*)d_in[7];
  const float* b2         = (const float*)d_in[8];
  float* out = (float*)d_out;

  char* ws = (char*)d_ws;
  unsigned short* concat = (unsigned short*)ws;               // [0, 3.15MB)
  float*          Hpart  = (float*)(ws + 3145728);            // [3.15MB, 16.25MB) 8*256*1600*4
  // partials/meta ALIAS Hpart's region (consumed by pool_merge before
  // gemm1 writes Hpart; stream-serial so no hazard):
  unsigned short* partials = (unsigned short*)Hpart;           // 8192*768*2 = 12,582,912 B
  float4*         meta     = (float4*)(ws + 3145728 + 12582912); // 8192*16 = 131,072 B

  hipLaunchKernelGGL(pool_partial, dim3(8192), dim3(256), 0, stream,
                     left, right, femb_l, femb_r, partials, meta);
  hipLaunchKernelGGL(pool_merge, dim3(2048), dim3(192), 0, stream,
                     partials, meta, empty_attr, concat);
  hipLaunchKernelGGL(gemm1_kernel, dim3(100, 8), dim3(256), 0, stream,
                     concat, W1, Hpart);
  hipLaunchKernelGGL(epilogue_kernel, dim3(256), dim3(256), 0, stream,
                     Hpart, b1, W2, b2, out);
}

// Round 8
// 138.033 us; speedup vs baseline: 1.0114x; 1.0114x over previous
//
#include <hip/hip_runtime.h>

typedef __attribute__((ext_vector_type(8))) short short8;
typedef __attribute__((ext_vector_type(4))) short short4_t;
typedef __attribute__((ext_vector_type(4))) float f32x4;

#define NEGBIG -1e10f

__device__ __forceinline__ unsigned short f2bf(float x) {
  unsigned int u = __float_as_uint(x);
  u += 0x7FFFu + ((u >> 16) & 1u);          // round-to-nearest-even
  return (unsigned short)(u >> 16);
}
__device__ __forceinline__ float bfu(unsigned short h) { return __uint_as_float(((unsigned)h) << 16); }

__device__ __forceinline__ float4 mul4(float4 a, float s) {
  float4 r; r.x = a.x*s; r.y = a.y*s; r.z = a.z*s; r.w = a.w*s; return r;
}
__device__ __forceinline__ float4 add4(float4 a, float4 b) {
  float4 r; r.x = a.x+b.x; r.y = a.y+b.y; r.z = a.z+b.z; r.w = a.w+b.w; return r;
}

// async global->LDS DMA, 16B per lane. LDS dest must be wave-uniform
// (lane l lands at l*16B past it); global src is per-lane.
__device__ __forceinline__ void g2l16(const float* g, float* l) {
  __builtin_amdgcn_global_load_lds(
      (const __attribute__((address_space(1))) void*)g,
      (__attribute__((address_space(3))) void*)l,
      16, 0, 0);
}

// ---------------- pool partial: quarter-panel via async LDS staging --------
// Grid 8192 = 2048 panels x 4 quarters. Block = 4 waves; wave owns 4 tokens.
// Each wave issues 12 global_load_lds (NO VGPRs consumed -> all 12 in flight,
// breaking the register-pressure load serialization seen in R3-R7), waits
// vmcnt(0) once, then all compute reads the 49KB f32 panel from LDS.
__global__ __launch_bounds__(256) void pool_partial(
    const float* __restrict__ left, const float* __restrict__ right,
    const float* __restrict__ femb_l, const float* __restrict__ femb_r,
    unsigned short* __restrict__ partials,   // [8192][768] bf16 (unnormalized)
    float4* __restrict__ meta)               // [8192] (M, S, nz, 0)
{
  int bid     = blockIdx.x;     // 0..8191
  int panel   = bid >> 2;       // 0..2047
  int quarter = bid & 3;
  int side    = panel >> 10;
  int rem     = panel & 1023;   // b*4 + f
  int f       = rem & 3;
  const float* v    = (side ? right : left) + (size_t)rem * 64 * 768 + (size_t)quarter * 16 * 768;
  const float* femb = (side ? femb_r : femb_l) + f * 768;

  int tid = threadIdx.x, wave = tid >> 6, lane = tid & 63;

  __shared__ float    panel_lds[16 * 768];   // 49152 B
  __shared__ float    l_lds[16];
  __shared__ unsigned nz_lds[4];

  // femb fragment (cached reads; also covered by the vmcnt wait below)
  const float4* fp = (const float4*)femb;
  float4 f0 = fp[lane], f1 = fp[lane + 64], f2 = fp[lane + 128];

  // ---- Phase 0: issue 12 async DMA loads for this wave's 4 tokens ----
  const float* vw = v + (size_t)wave * 4 * 768;
  float*       lw = panel_lds + wave * 4 * 768;
  #pragma unroll
  for (int t = 0; t < 4; ++t) {
    #pragma unroll
    for (int j = 0; j < 3; ++j)
      g2l16(vw + t * 768 + j * 256 + lane * 4, lw + t * 768 + j * 256);
  }
  asm volatile("s_waitcnt vmcnt(0)" ::: "memory");

  // ---- Phase 1: per-wave logits from LDS (4 tokens) ----
  const float4* pw = (const float4*)lw;
  float d[4];
  unsigned nzmask = 0;
  #pragma unroll
  for (int t = 0; t < 4; ++t) {
    float4 x0 = pw[t * 192 + lane];
    float4 x1 = pw[t * 192 + 64 + lane];
    float4 x2 = pw[t * 192 + 128 + lane];
    d[t] = x0.x*f0.x + x0.y*f0.y + x0.z*f0.z + x0.w*f0.w
         + x1.x*f1.x + x1.y*f1.y + x1.z*f1.z + x1.w*f1.w
         + x2.x*f2.x + x2.y*f2.y + x2.z*f2.z + x2.w*f2.w;
    unsigned nzb = __float_as_uint(x0.x) | __float_as_uint(x0.y)
                 | __float_as_uint(x0.z) | __float_as_uint(x0.w)
                 | __float_as_uint(x1.x) | __float_as_uint(x1.y)
                 | __float_as_uint(x1.z) | __float_as_uint(x1.w)
                 | __float_as_uint(x2.x) | __float_as_uint(x2.y)
                 | __float_as_uint(x2.z) | __float_as_uint(x2.w);
    nzmask |= (nzb != 0u) ? (1u << t) : 0u;
  }
  #pragma unroll
  for (int sh = 32; sh > 0; sh >>= 1) {
    d[0] += __shfl_xor(d[0], sh);
    d[1] += __shfl_xor(d[1], sh);
    d[2] += __shfl_xor(d[2], sh);
    d[3] += __shfl_xor(d[3], sh);
    nzmask |= __shfl_xor(nzmask, sh);
  }
  if (lane == 0) {
    #pragma unroll
    for (int t = 0; t < 4; ++t)
      l_lds[wave * 4 + t] = d[t] + (((nzmask >> t) & 1u) ? 0.f : NEGBIG);
    nz_lds[wave] = nzmask & 0xFu;
  }
  __syncthreads();   // panel DMA + logits all visible block-wide

  // ---- Phase 2: block softmax weights + column-wise summary ----
  float lv[16];
  #pragma unroll
  for (int t = 0; t < 16; ++t) lv[t] = l_lds[t];
  float M = lv[0];
  #pragma unroll
  for (int t = 1; t < 16; ++t) M = fmaxf(M, lv[t]);
  float e[16]; float S = 0.f;
  #pragma unroll
  for (int t = 0; t < 16; ++t) { e[t] = __expf(lv[t] - M); S += e[t]; }
  unsigned has = nz_lds[0] | nz_lds[1] | nz_lds[2] | nz_lds[3];

  if (tid < 192) {
    const float4* pf = (const float4*)panel_lds;
    float4 acc = {0.f, 0.f, 0.f, 0.f};
    #pragma unroll
    for (int t = 0; t < 16; ++t) {
      float4 x = pf[t * 192 + tid];
      acc.x += e[t] * x.x; acc.y += e[t] * x.y;
      acc.z += e[t] * x.z; acc.w += e[t] * x.w;
    }
    ushort4 o;
    o.x = f2bf(acc.x); o.y = f2bf(acc.y); o.z = f2bf(acc.z); o.w = f2bf(acc.w);
    ((ushort4*)(partials + (size_t)bid * 768))[tid] = o;
  }
  if (tid == 192) {
    float4 mt; mt.x = M; mt.y = S; mt.z = has ? 1.f : 0.f; mt.w = 0.f;
    meta[bid] = mt;
  }
}

// ---------------- pool merge: combine 4 quarter-panels -> bf16 concat ------
__global__ __launch_bounds__(192) void pool_merge(
    const unsigned short* __restrict__ partials, const float4* __restrict__ meta,
    const float* __restrict__ empty_attr,
    unsigned short* __restrict__ concat)   // [B, 8, 768] bf16
{
  int panel = blockIdx.x;     // 0..2047
  int tid = threadIdx.x;      // 0..191
  int side = panel >> 10;
  int rem  = panel & 1023;
  int f    = rem & 3;
  int b    = rem >> 2;

  int p4 = panel * 4;
  float4 mt0 = meta[p4], mt1 = meta[p4 + 1], mt2 = meta[p4 + 2], mt3 = meta[p4 + 3];
  float M = fmaxf(fmaxf(mt0.x, mt1.x), fmaxf(mt2.x, mt3.x));
  float sc0 = __expf(mt0.x - M), sc1 = __expf(mt1.x - M);
  float sc2 = __expf(mt2.x - M), sc3 = __expf(mt3.x - M);
  float S = mt0.y * sc0 + mt1.y * sc1 + mt2.y * sc2 + mt3.y * sc3;
  int has = (mt0.z + mt1.z + mt2.z + mt3.z) != 0.f;

  ushort4 q0 = ((const ushort4*)(partials + (size_t)(p4 + 0) * 768))[tid];
  ushort4 q1 = ((const ushort4*)(partials + (size_t)(p4 + 1) * 768))[tid];
  ushort4 q2 = ((const ushort4*)(partials + (size_t)(p4 + 2) * 768))[tid];
  ushort4 q3 = ((const ushort4*)(partials + (size_t)(p4 + 3) * 768))[tid];

  float4 r;
  if (has) {
    float i0 = sc0 / S, i1 = sc1 / S, i2 = sc2 / S, i3 = sc3 / S;
    r.x = bfu(q0.x)*i0 + bfu(q1.x)*i1 + bfu(q2.x)*i2 + bfu(q3.x)*i3;
    r.y = bfu(q0.y)*i0 + bfu(q1.y)*i1 + bfu(q2.y)*i2 + bfu(q3.y)*i3;
    r.z = bfu(q0.z)*i0 + bfu(q1.z)*i1 + bfu(q2.z)*i2 + bfu(q3.z)*i3;
    r.w = bfu(q0.w)*i0 + bfu(q1.w)*i1 + bfu(q2.w)*i2 + bfu(q3.w)*i3;
  } else {
    r = ((const float4*)empty_attr)[tid];
  }
  ushort4 o;
  o.x = f2bf(r.x); o.y = f2bf(r.y); o.z = f2bf(r.z); o.w = f2bf(r.w);
  size_t base = ((size_t)b * 8 + side * 4 + f) * 192;
  ((ushort4*)concat)[base + tid] = o;
}

// ---------------- GEMM1 split-K ----------------
// A [256,6144] bf16 (K-contig). W1 [1600,6144] f32 (K-contig).
// Grid (100 col-tiles, 8 K-chunks). Each block stages its EXCLUSIVE
// 16col x 768K W1 tile in LDS (bf16) -> W1 read once total.
__global__ __launch_bounds__(256) void gemm1_kernel(
    const unsigned short* __restrict__ A,
    const float* __restrict__ W1,
    float* __restrict__ Hpart)
{
  const int K = 6144, N = 1600, KC = 768;
  int colb = blockIdx.x;          // 0..99
  int kc   = blockIdx.y;          // 0..7
  int col0 = colb * 16;
  int tid = threadIdx.x, wave = tid >> 6, lane = tid & 63;

  __shared__ short wlds[96 * 16 * 8];

  const float* wsrc = W1 + (size_t)col0 * K + kc * KC;
  #pragma unroll
  for (int i = 0; i < 12; ++i) {
    int flat4 = tid + 256 * i;
    int col = flat4 / 192;
    int k   = (flat4 % 192) * 4;
    float4 w = *(const float4*)(wsrc + (size_t)col * K + k);
    short4_t o;
    o[0] = (short)f2bf(w.x); o[1] = (short)f2bf(w.y);
    o[2] = (short)f2bf(w.z); o[3] = (short)f2bf(w.w);
    *(short4_t*)(wlds + (k >> 3) * 128 + col * 8 + (k & 7)) = o;
  }
  __syncthreads();

  int lr = lane & 15;
  const short* a0 = (const short*)A + (size_t)(wave * 64 + lr) * K + kc * KC + (lane >> 4) * 8;
  const short* bptr = wlds + (lane >> 4) * 128 + lr * 8;

  f32x4 acc0 = {}, acc1 = {}, acc2 = {}, acc3 = {};

  #pragma unroll 4
  for (int ks = 0; ks < 24; ++ks) {
    short8 bf  = *(const short8*)(bptr + ks * 512);
    short8 af0 = *(const short8*)(a0 + ks * 32);
    short8 af1 = *(const short8*)(a0 + ks * 32 + 16 * K);
    short8 af2 = *(const short8*)(a0 + ks * 32 + 32 * K);
    short8 af3 = *(const short8*)(a0 + ks * 32 + 48 * K);
    acc0 = __builtin_amdgcn_mfma_f32_16x16x32_bf16(af0, bf, acc0, 0, 0, 0);
    acc1 = __builtin_amdgcn_mfma_f32_16x16x32_bf16(af1, bf, acc1, 0, 0, 0);
    acc2 = __builtin_amdgcn_mfma_f32_16x16x32_bf16(af2, bf, acc2, 0, 0, 0);
    acc3 = __builtin_amdgcn_mfma_f32_16x16x32_bf16(af3, bf, acc3, 0, 0, 0);
  }

  int ccol = lane & 15;
  int crow = (lane >> 4) * 4;
  float* hp = Hpart + (size_t)kc * 256 * N + (size_t)col0 + ccol;
  f32x4 accs[4] = {acc0, acc1, acc2, acc3};
  #pragma unroll
  for (int i = 0; i < 4; ++i) {
    int r = wave * 64 + i * 16 + crow;
    #pragma unroll
    for (int q = 0; q < 4; ++q)
      hp[(size_t)(r + q) * N] = accs[i][q];
  }
}

// ---------------- epilogue: reduce split-K + bias + relu + head GEMM -------
__global__ __launch_bounds__(256) void epilogue_kernel(
    const float* __restrict__ Hpart, const float* __restrict__ b1,
    const float* __restrict__ W2, const float* __restrict__ b2,
    float* __restrict__ out)
{
  const int N = 1600;
  int b = blockIdx.x, tid = threadIdx.x;
  int wave = tid >> 6, lane = tid & 63;
  float s0 = 0.f, s1 = 0.f;
  for (int c = tid; c < N; c += 256) {
    float acc = 0.f;
    #pragma unroll
    for (int kc = 0; kc < 8; ++kc)
      acc += Hpart[((size_t)kc * 256 + b) * N + c];
    float h = fmaxf(acc + b1[c], 0.f);
    s0 += h * W2[c];
    s1 += h * W2[N + c];
  }
  #pragma unroll
  for (int s = 32; s > 0; s >>= 1) {
    s0 += __shfl_xor(s0, s);
    s1 += __shfl_xor(s1, s);
  }
  __shared__ float r0[4], r1[4];
  if (lane == 0) { r0[wave] = s0; r1[wave] = s1; }
  __syncthreads();
  if (tid == 0) {
    out[b * 2 + 0] = r0[0] + r0[1] + r0[2] + r0[3] + b2[0];
    out[b * 2 + 1] = r1[0] + r1[1] + r1[2] + r1[3] + b2[1];
  }
}

extern "C" void kernel_launch(void* const* d_in, const int* in_sizes, int n_in,
                              void* d_out, int out_size, void* d_ws, size_t ws_size,
                              hipStream_t stream) {
  const float* left       = (const float*)d_in[0];
  const float* right      = (const float*)d_in[1];
  const float* femb_l     = (const float*)d_in[2];
  const float* femb_r     = (const float*)d_in[3];
  const float* empty_attr = (const float*)d_in[4];
  const float* W1         = (const float*)d_in[5];
  const float* b1         = (const float*)d_in[6];
  const float* W2         = (const float*)d_in[7];
  const float* b2         = (const float*)d_in[8];
  float* out = (float*)d_out;

  char* ws = (char*)d_ws;
  unsigned short* concat = (unsigned short*)ws;               // [0, 3.15MB)
  float*          Hpart  = (float*)(ws + 3145728);            // [3.15MB, 16.25MB) 8*256*1600*4
  // partials/meta ALIAS Hpart's region (consumed by pool_merge before
  // gemm1 writes Hpart; stream-serial so no hazard):
  unsigned short* partials = (unsigned short*)Hpart;           // 8192*768*2 = 12,582,912 B
  float4*         meta     = (float4*)(ws + 3145728 + 12582912); // 8192*16 = 131,072 B

  hipLaunchKernelGGL(pool_partial, dim3(8192), dim3(256), 0, stream,
                     left, right, femb_l, femb_r, partials, meta);
  hipLaunchKernelGGL(pool_merge, dim3(2048), dim3(192), 0, stream,
                     partials, meta, empty_attr, concat);
  hipLaunchKernelGGL(gemm1_kernel, dim3(100, 8), dim3(256), 0, stream,
                     concat, W1, Hpart);
  hipLaunchKernelGGL(epilogue_kernel, dim3(256), dim3(256), 0, stream,
                     Hpart, b1, W2, b2, out);
}